// Round 11
// baseline (661.911 us; speedup 1.0000x reference)
//
#include <hip/hip_runtime.h>

typedef unsigned short u16;
typedef unsigned int u32;
typedef __bf16 bf16x8 __attribute__((ext_vector_type(8)));
typedef float f32x4 __attribute__((ext_vector_type(4)));
typedef float f32x16 __attribute__((ext_vector_type(16)));

__device__ inline float bf2f(u16 u) { u32 x = ((u32)u) << 16; return __uint_as_float(x); }
__device__ inline u16 f2bf(float f) {
  u32 x = __float_as_uint(f);
  u32 r = (x + 0x7FFFu + ((x >> 16) & 1u)) >> 16;  // RNE
  return (u16)r;
}
__device__ inline u32 pack2(float lo, float hi) {
  return (u32)f2bf(lo) | ((u32)f2bf(hi) << 16);
}

// ---------------- cast x (f32 -> bf16) ----------------
__global__ __launch_bounds__(256) void cast_bf16(const float* __restrict__ s,
                                                 u16* __restrict__ d, int n4) {
  const float4* s4 = (const float4*)s;
  u32* d2 = (u32*)d;
  int i = blockIdx.x * 256 + threadIdx.x;
  int stride = gridDim.x * 256;
  for (; i < n4; i += stride) {
    float4 f = s4[i];
    d2[2 * i]     = pack2(f.x, f.y);
    d2[2 * i + 1] = pack2(f.z, f.w);
  }
}

// ---------------- transpose + cast: src[R][C] f32 -> dst[C][R] bf16 ----------------
__global__ __launch_bounds__(256) void transpose_cast(const float* __restrict__ src,
                                                      u16* __restrict__ dst, int R, int C) {
  __shared__ float tile[32][33];
  int bx = blockIdx.x, by = blockIdx.y;
  int tx = threadIdx.x & 31, ty = threadIdx.x >> 5;
  for (int rr = ty; rr < 32; rr += 8)
    tile[rr][tx] = src[(size_t)(by * 32 + rr) * C + bx * 32 + tx];
  __syncthreads();
  for (int rr = ty; rr < 32; rr += 8)
    dst[(size_t)(bx * 32 + rr) * R + by * 32 + tx] = f2bf(tile[tx][rr]);
}

// ======== 256x256 MFMA GEMM with 32x32x16 shape, 4-phase / 2-K-tile schedule ========
// Per phase: {ds_read frags, stage 1 tile-half-pair (4 loads), barrier, lgkm0, 16 MFMA}.
// Stages: ph0->buf1.B(t+1), ph1->buf0.A(t+2), ph2->buf0.B(t+2), ph3->buf1.A(t+3).
// vmcnt(4) at ph1/ph3 drains exactly what the next two phases need (ledger-verified).
#define MFMA32(AF, BF, NO)                                                        \
  _Pragma("unroll") for (int ks = 0; ks < 4; ++ks)                                \
  _Pragma("unroll") for (int mf = 0; mf < 4; ++mf)                                \
    acc[mf][NO] = __builtin_amdgcn_mfma_f32_32x32x16_bf16(                        \
        AF[mf][ks], BF[ks], acc[mf][NO], 0, 0, 0);

#define PH_OPEN                                                                   \
  __builtin_amdgcn_s_barrier();                                                   \
  asm volatile("s_waitcnt lgkmcnt(0)" ::: "memory");                              \
  __builtin_amdgcn_sched_barrier(0);                                              \
  __builtin_amdgcn_s_setprio(1);

#define PH_CLOSE                                                                  \
  __builtin_amdgcn_s_setprio(0);                                                  \
  __builtin_amdgcn_s_barrier();                                                   \
  __builtin_amdgcn_sched_barrier(0);

#define PH_CLOSE_VM                                                               \
  __builtin_amdgcn_s_setprio(0);                                                  \
  asm volatile("s_waitcnt vmcnt(4)" ::: "memory");                                \
  __builtin_amdgcn_s_barrier();                                                   \
  __builtin_amdgcn_sched_barrier(0);

template <int EPI>
__global__ __launch_bounds__(512, 2) void gemm32(
    const u16* __restrict__ A, const u16* __restrict__ Bt, int M, int N, int K, int NB,
    u16* __restrict__ q0, u16* __restrict__ k0, u16* __restrict__ v0,
    u16* __restrict__ q4, u16* __restrict__ k4, u16* __restrict__ v4,
    float* __restrict__ out, const float* __restrict__ bias) {
  __shared__ u16 lds[2][2][16384];   // [buf][A/B][256 rows * 64 k]
  const int tid = threadIdx.x;
  const int lane = tid & 63;
  const int wave = tid >> 6;
  const int wm = wave >> 2, wn = wave & 3;
  const int l31 = lane & 31, hk = lane >> 5;
  (void)M;

  const int nwg = gridDim.x;
  const int bid = blockIdx.x;
  const int swz = (bid & 7) * (nwg >> 3) + (bid >> 3);
  const int m0 = (swz / NB) * 256;
  const int n0 = (swz % NB) * 256;
  const int NT = K >> 6;
  const int NI = NT >> 1;

  auto stage_half = [&](int buf, int ht, int kt_) {
    const u16* src = (ht < 2) ? A : Bt;
    const int r0 = (ht < 2) ? m0 : n0;
    u16* ldsop = &lds[buf][ht >> 1][0];
#pragma unroll
    for (int ii = 0; ii < 2; ++ii) {
      int c2 = ((ht & 1) * 2 + ii) * 512 + tid;
      int row = c2 >> 3, ps = c2 & 7;
      int ks = ps ^ (row & 7);
      const u16* g = src + (size_t)(r0 + row) * K + kt_ + ks * 8;
      char* l = (char*)ldsop + (size_t)((((ht & 1) * 2 + ii) * 512 + (tid & ~63)) * 16);
      __builtin_amdgcn_global_load_lds((const __attribute__((address_space(1))) void*)g,
                                       (__attribute__((address_space(3))) void*)l, 16, 0, 0);
    }
  };
  // A frag (32x32x16): row = l31, k = hk*8 + e  -> 16B at slot (ks*2+hk)^(row&7)
  auto rdA = [&](int c, int mf, int ks) -> bf16x8 {
    int rl = wm * 128 + mf * 32 + l31;
    int sl = (ks * 2 + hk) ^ (rl & 7);
    return *(const bf16x8*)(&lds[c][0][rl * 64 + sl * 8]);
  };
  auto rdB = [&](int c, int nf, int ks) -> bf16x8 {
    int rl = wn * 64 + nf * 32 + l31;
    int sl = (ks * 2 + hk) ^ (rl & 7);
    return *(const bf16x8*)(&lds[c][1][rl * 64 + sl * 8]);
  };

  f32x16 acc[4][2];
#pragma unroll
  for (int mf = 0; mf < 4; ++mf)
#pragma unroll
    for (int nf = 0; nf < 2; ++nf)
#pragma unroll
      for (int r = 0; r < 16; ++r) acc[mf][nf][r] = 0.f;

  // prologue: buf0 full (tile0, oldest 8 loads), buf1.A (tile1); drain buf0
  const int k1t = ((NT > 1) ? 1 : 0) << 6;
  stage_half(0, 0, 0); stage_half(0, 1, 0);
  stage_half(0, 2, 0); stage_half(0, 3, 0);
  stage_half(1, 0, k1t); stage_half(1, 1, k1t);
  asm volatile("s_waitcnt vmcnt(4)" ::: "memory");
  __builtin_amdgcn_s_barrier();
  __builtin_amdgcn_sched_barrier(0);

  bf16x8 af[4][4], bfr[4];
  for (int it = 0; it < NI; ++it) {
    const int kO  = (2 * it + 1) << 6;
    const int t2  = 2 * it + 2, t3 = 2 * it + 3;
    const int kE2 = ((t2 < NT) ? t2 : NT - 1) << 6;
    const int kO2 = ((t3 < NT) ? t3 : NT - 1) << 6;

    // ph0: even tile (buf0): A all ksteps + B nf0; stage buf1.B (tile t+1)
#pragma unroll
    for (int mf = 0; mf < 4; ++mf)
#pragma unroll
      for (int ks = 0; ks < 4; ++ks) af[mf][ks] = rdA(0, mf, ks);
#pragma unroll
    for (int ks = 0; ks < 4; ++ks) bfr[ks] = rdB(0, 0, ks);
    stage_half(1, 2, kO); stage_half(1, 3, kO);
    PH_OPEN MFMA32(af, bfr, 0) PH_CLOSE
    // ph1: B nf1 (A held); stage buf0.A (tile t+2); drain ph-1..ph0 stages
#pragma unroll
    for (int ks = 0; ks < 4; ++ks) bfr[ks] = rdB(0, 1, ks);
    stage_half(0, 0, kE2); stage_half(0, 1, kE2);
    PH_OPEN MFMA32(af, bfr, 1) PH_CLOSE_VM
    // ph2: odd tile (buf1): A all + B nf0; stage buf0.B (tile t+2)
#pragma unroll
    for (int mf = 0; mf < 4; ++mf)
#pragma unroll
      for (int ks = 0; ks < 4; ++ks) af[mf][ks] = rdA(1, mf, ks);
#pragma unroll
    for (int ks = 0; ks < 4; ++ks) bfr[ks] = rdB(1, 0, ks);
    stage_half(0, 2, kE2); stage_half(0, 3, kE2);
    PH_OPEN MFMA32(af, bfr, 0) PH_CLOSE
    // ph3: B nf1 (A held); stage buf1.A (tile t+3); drain ph1..ph2 stages
#pragma unroll
    for (int ks = 0; ks < 4; ++ks) bfr[ks] = rdB(1, 1, ks);
    stage_half(1, 0, kO2); stage_half(1, 1, kO2);
    PH_OPEN MFMA32(af, bfr, 1) PH_CLOSE_VM
  }
  asm volatile("s_waitcnt vmcnt(0)" ::: "memory");

  // ---- epilogue: C/D map col=lane&31, row=(r&3)+8*(r>>2)+4*(lane>>5)
#pragma unroll
  for (int mf = 0; mf < 4; ++mf) {
#pragma unroll
    for (int nf = 0; nf < 2; ++nf) {
      int col = n0 + wn * 64 + nf * 32 + l31;
      if (EPI == 0) {
        int p = col >> 10, cc = col & 1023;
        int h = cc >> 6, d = cc & 63;
        u16* dst = (p == 0) ? q0 : (p == 1) ? k0 : v0;
        float sc = (p == 0) ? 0.125f : 1.0f;
#pragma unroll
        for (int r = 0; r < 16; ++r) {
          int row = m0 + wm * 128 + mf * 32 + (r & 3) + 8 * (r >> 2) + 4 * hk;
          int b = row >> 13, nn = row & 8191;
          dst[((size_t)((b << 4) + h) * 8192 + nn) * 64 + d] = f2bf(acc[mf][nf][r] * sc);
        }
        // level-4 pooled: rows 0-15 of this frag = regs 0-7 (both hk), rows 16-31 = regs 8-15
        float sA = 0.f, sB = 0.f;
#pragma unroll
        for (int r = 0; r < 8; ++r) { sA += acc[mf][nf][r]; sB += acc[mf][nf][8 + r]; }
        sA += __shfl_xor(sA, 32);
        sB += __shfl_xor(sB, 32);
        if (lane < 32) {
          u16* dst4 = (p == 0) ? q4 : (p == 1) ? k4 : v4;
#pragma unroll
          for (int hf = 0; hf < 2; ++hf) {
            float sv = hf ? sB : sA;
            int row = m0 + wm * 128 + mf * 32 + hf * 16;
            int b = row >> 13, n4 = (row & 8191) >> 4;
            float val = (p == 2) ? sv : sv * 0.0625f;
            if (p == 0) val *= 0.125f;
            dst4[((size_t)((b << 4) + h) * 512 + n4) * 64 + d] = f2bf(val);
          }
        }
      } else {
        float bv = bias[col];
#pragma unroll
        for (int r = 0; r < 16; ++r) {
          int row = m0 + wm * 128 + mf * 32 + (r & 3) + 8 * (r >> 2) + 4 * hk;
          out[(size_t)row * N + col] = acc[mf][nf][r] + bv;
        }
      }
    }
  }
}

// ---------------- fused pooling: levels 5-8 directly from level 4 ----------------
__global__ __launch_bounds__(256) void pool_all4(
    const u16* __restrict__ q4, const u16* __restrict__ k4, const u16* __restrict__ v4,
    u16* __restrict__ qd, u16* __restrict__ kd, u16* __restrict__ vd) {
  int t = blockIdx.x * 256 + threadIdx.x;
  if (t >= 983040) return;  // 64 * 480 * 32
  int arr = blockIdx.y;
  int col = t & 31;
  int rr = t >> 5;
  int Bi = rr / 480;
  int r = rr % 480;
  int base, w, Nl;
  if (r < 256)      { base = 0;   w = 2;  Nl = 256; }
  else if (r < 384) { base = 256; w = 4;  Nl = 128; r -= 256; }
  else if (r < 448) { base = 384; w = 8;  Nl = 64;  r -= 384; }
  else              { base = 448; w = 16; Nl = 32;  r -= 448; }
  const u32* s = (const u32*)(arr == 0 ? q4 : arr == 1 ? k4 : v4);
  const u32* src = s + ((size_t)Bi * 512 + (size_t)r * w) * 32 + col;
  float lo = 0, hi = 0;
  for (int m = 0; m < w; ++m) {
    u32 u = src[(size_t)m * 32];
    lo += bf2f((u16)u); hi += bf2f((u16)(u >> 16));
  }
  float sc = (arr == 2) ? 1.0f : (1.0f / (float)w);
  u32* d = (u32*)(arr == 0 ? qd : arr == 1 ? kd : vd);
  d[(size_t)2048 * base + ((size_t)Bi * Nl + r) * 32 + col] = pack2(lo * sc, hi * sc);
}

// ---------------- coarse attention: all levels 4-8 in one launch, always flip ----------------
__global__ __launch_bounds__(256) void hattn_coarse(
    const u16* __restrict__ q4, const u16* __restrict__ k4, const u16* __restrict__ v4,
    const u16* __restrict__ qc, const u16* __restrict__ kc, const u16* __restrict__ vc,
    float* __restrict__ ylvl, float* __restrict__ alvl) {
  __shared__ float qs[16][68], ks[16][68], vs[16][68];
  __shared__ float As[16][17];
  const int bx = blockIdx.x, Bi = blockIdx.y;
  int lvl, jb;
  if (bx < 32)      { lvl = 0; jb = bx; }
  else if (bx < 48) { lvl = 1; jb = bx - 32; }
  else if (bx < 56) { lvl = 2; jb = bx - 48; }
  else if (bx < 60) { lvl = 3; jb = bx - 56; }
  else              { lvl = 4; jb = bx - 60; }
  const int N = 512 >> lvl;
  const int srcb[5] = {0, 0, 256, 384, 448};
  const int offr[5] = {0, 512, 768, 896, 960};
  const u16* qp = (lvl == 0) ? q4 : qc + (size_t)4096 * srcb[lvl];
  const u16* kp = (lvl == 0) ? k4 : kc + (size_t)4096 * srcb[lvl];
  const u16* vp = (lvl == 0) ? v4 : vc + (size_t)4096 * srcb[lvl];
  const int tid = threadIdx.x;
  const int jk = jb ^ 1;
  const u32* qg = (const u32*)(qp + ((size_t)Bi * N + jb * 16) * 64);
  const u32* kg = (const u32*)(kp + ((size_t)Bi * N + jk * 16) * 64);
  const u32* vg = (const u32*)(vp + ((size_t)Bi * N + jk * 16) * 64);
#pragma unroll
  for (int u = tid; u < 512; u += 256) {
    int row = u >> 5, dp = (u & 31) * 2;
    u32 a = qg[u]; qs[row][dp] = bf2f((u16)a); qs[row][dp + 1] = bf2f((u16)(a >> 16));
    u32 b = kg[u]; ks[row][dp] = bf2f((u16)b); ks[row][dp + 1] = bf2f((u16)(b >> 16));
    u32 c = vg[u]; vs[row][dp] = bf2f((u16)c); vs[row][dp + 1] = bf2f((u16)(c >> 16));
  }
  __syncthreads();
  const int i = tid >> 4, j = tid & 15;
  float s = 0.f;
  const float4* qv = (const float4*)&qs[i][0];
  const float4* kv = (const float4*)&ks[j][0];
#pragma unroll
  for (int d4 = 0; d4 < 16; ++d4) {
    float4 a = qv[d4], b = kv[d4];
    s += a.x * b.x + a.y * b.y + a.z * b.z + a.w * b.w;
  }
  float mx = s;
#pragma unroll
  for (int off = 8; off; off >>= 1) mx = fmaxf(mx, __shfl_xor(mx, off, 16));
  float aexp = __expf(s - mx);
  float asum = aexp;
#pragma unroll
  for (int off = 8; off; off >>= 1) asum += __shfl_xor(asum, off, 16);
  As[i][j] = aexp;
  __syncthreads();
  float y0 = 0, y1 = 0, y2 = 0, y3 = 0;
  const int d0 = j * 4;
#pragma unroll
  for (int jj = 0; jj < 16; ++jj) {
    float av = As[i][jj];
    const float4 vv = *(const float4*)&vs[jj][d0];
    y0 += av * vv.x; y1 += av * vv.y; y2 += av * vv.z; y3 += av * vv.w;
  }
  const int nf = jb * 16 + i;
  float* yo = ylvl + (size_t)4096 * offr[lvl] + ((size_t)Bi * N + nf) * 64 + d0;
  yo[0] = y0; yo[1] = y1; yo[2] = y2; yo[3] = y3;
  if (j == 0) alvl[(size_t)64 * offr[lvl] + (size_t)Bi * N + nf] = asum;
}

// ================= fused fine attention (levels 3..0), MFMA =================
union F8 { u32 w[4]; bf16x8 v; };

__device__ inline void acc_row8(const u16* p, float* a) {
  const u32* qw = (const u32*)p;
#pragma unroll
  for (int m = 0; m < 4; ++m) {
    u32 u = qw[m];
    a[2 * m]     += bf2f((u16)u);
    a[2 * m + 1] += bf2f((u16)(u >> 16));
  }
}
__device__ inline bf16x8 mk8(const float* a, float s) {
  F8 f;
#pragma unroll
  for (int m = 0; m < 4; ++m) f.w[m] = pack2(a[2 * m] * s, a[2 * m + 1] * s);
  return f.v;
}
__device__ inline bf16x8 pool_frag(const u16* arr, int row0, int cnt, int slotq, float scale) {
  float a[8] = {0, 0, 0, 0, 0, 0, 0, 0};
  for (int m = 0; m < cnt; ++m) {
    int r = row0 + m;
    acc_row8(arr + r * 64 + ((slotq ^ (r & 7)) * 8), a);
  }
  return mk8(a, scale);
}
__device__ inline bf16x8 rd_frag(const u16* arr, int r, int slotq) {
  return *(const bf16x8*)(arr + r * 64 + ((slotq ^ (r & 7)) * 8));
}
template <int LVL>
__device__ inline bf16x8 vt_frag(const u16* Vt, int c, int rbase) {
  float a[8] = {0, 0, 0, 0, 0, 0, 0, 0};
  const u32* p = (const u32*)(Vt + c * 266 + rbase);
#pragma unroll
  for (int g = 0; g < (1 << LVL); ++g) {
#pragma unroll
    for (int m = 0; m < 4; ++m) {
      u32 u = p[g * 4 + m];
      int t = g * 8 + 2 * m;
      a[t >> LVL]       += bf2f((u16)u);
      a[(t + 1) >> LVL] += bf2f((u16)(u >> 16));
    }
  }
  return mk8(a, 1.0f);
}

__device__ inline bf16x8 qk_softmax(bf16x8 ka0, bf16x8 ka1, bf16x8 qb0, bf16x8 qb1,
                                    int lane, float* asum_out) {
  f32x4 s = {0.f, 0.f, 0.f, 0.f};
  s = __builtin_amdgcn_mfma_f32_16x16x32_bf16(ka0, qb0, s, 0, 0, 0);
  s = __builtin_amdgcn_mfma_f32_16x16x32_bf16(ka1, qb1, s, 0, 0, 0);
  float mx = fmaxf(fmaxf(s[0], s[1]), fmaxf(s[2], s[3]));
  mx = fmaxf(mx, __shfl_xor(mx, 32));
  mx = fmaxf(mx, __shfl_xor(mx, 16));
  float p0 = __expf(s[0] - mx), p1 = __expf(s[1] - mx);
  float p2 = __expf(s[2] - mx), p3 = __expf(s[3] - mx);
  float as = p0 + p1 + p2 + p3;
  as += __shfl_xor(as, 32);
  as += __shfl_xor(as, 16);
  *asum_out = as;
  u32 pk01 = pack2(p0, p1), pk23 = pack2(p2, p3);
  int jq = lane & 15, lg = lane >> 4;
  int a1 = ((((lg * 2) * 16) + jq) & 63) << 2;
  int a2 = ((((lg * 2 + 1) * 16) + jq) & 63) << 2;
  F8 f;
  f.w[0] = (u32)__builtin_amdgcn_ds_bpermute(a1, (int)pk01);
  f.w[1] = (u32)__builtin_amdgcn_ds_bpermute(a1, (int)pk23);
  f.w[2] = (u32)__builtin_amdgcn_ds_bpermute(a2, (int)pk01);
  f.w[3] = (u32)__builtin_amdgcn_ds_bpermute(a2, (int)pk23);
  if (lg >= 2) { f.w[0] = 0; f.w[1] = 0; f.w[2] = 0; f.w[3] = 0; }
  return f.v;
}

__global__ __launch_bounds__(512, 1) void attn_fine(
    const u16* __restrict__ q, const u16* __restrict__ k, const u16* __restrict__ v,
    const float* __restrict__ ylvl, const float* __restrict__ alvl,
    u16* __restrict__ outA) {
  __shared__ u16 Qs[16384];
  __shared__ u16 Ks[16384];
  __shared__ u16 Vt[17024];       // [64][266] transposed, odd-word row stride
  __shared__ float Yc1[128][68];
  __shared__ float Yc2[64][68];
  __shared__ float Yc3[32][68];
  __shared__ float SUMc[224];
  const int tid = threadIdx.x;
  const int lane = tid & 63;
  const int wv = tid >> 6;
  const int j = lane & 15, lg = lane >> 4;
  const int ci = blockIdx.x, Bi = blockIdx.y;
  const size_t gbase = ((size_t)Bi * 8192 + (size_t)ci * 256) * 64;

#pragma unroll
  for (int it = 0; it < 4; ++it) {
    int sidx = it * 512 + tid;
    int row = sidx >> 3, ps = sidx & 7;
    int ks_ = ps ^ (row & 7);
    const u16* gq = q + gbase + (size_t)row * 64 + ks_ * 8;
    const u16* gk = k + gbase + (size_t)row * 64 + ks_ * 8;
    char* lq = (char*)Qs + (size_t)(it * 512 + (tid & ~63)) * 16;
    char* lk = (char*)Ks + (size_t)(it * 512 + (tid & ~63)) * 16;
    __builtin_amdgcn_global_load_lds((const __attribute__((address_space(1))) void*)gq,
                                     (__attribute__((address_space(3))) void*)lq, 16, 0, 0);
    __builtin_amdgcn_global_load_lds((const __attribute__((address_space(1))) void*)gk,
                                     (__attribute__((address_space(3))) void*)lk, 16, 0, 0);
  }
  {
    const uint4* gv = (const uint4*)(v + gbase);
    u32* Vt32 = (u32*)Vt;
#pragma unroll
    for (int it = 0; it < 2; ++it) {
      int i = it * 512 + tid;
      int r2 = i >> 3, cg = i & 7, c0 = cg * 8;
      uint4 a = gv[(size_t)(2 * r2) * 8 + cg];
      uint4 b = gv[(size_t)(2 * r2 + 1) * 8 + cg];
      const u16* pa = (const u16*)&a;
      const u16* pb = (const u16*)&b;
#pragma unroll
      for (int m = 0; m < 8; ++m)
        Vt32[(c0 + m) * 133 + r2] = (u32)pa[m] | ((u32)pb[m] << 16);
    }
  }
  __syncthreads();

  {
    int kb = wv ^ 1;
    bf16x8 ka0 = pool_frag(Ks, kb * 32 + 2 * j, 2, lg, 0.5f);
    bf16x8 ka1 = pool_frag(Ks, kb * 32 + 2 * j, 2, 4 + lg, 0.5f);
    bf16x8 qb0 = pool_frag(Qs, wv * 32 + 2 * j, 2, lg, 0.5f);
    bf16x8 qb1 = pool_frag(Qs, wv * 32 + 2 * j, 2, 4 + lg, 0.5f);
    float as;
    bf16x8 pa = qk_softmax(ka0, ka1, qb0, qb1, lane, &as);
    if (lg == 0) SUMc[wv * 16 + j] = as;
    int rb = kb * 32 + (lg & 1) * 16;
    f32x4 acc[4];
#pragma unroll
    for (int ch = 0; ch < 4; ++ch) {
      bf16x8 vb = vt_frag<1>(Vt, ch * 16 + j, rb);
      acc[ch] = __builtin_amdgcn_mfma_f32_16x16x32_bf16(pa, vb, f32x4{0.f,0.f,0.f,0.f}, 0, 0, 0);
    }
#pragma unroll
    for (int ch = 0; ch < 4; ++ch)
#pragma unroll
      for (int jj = 0; jj < 4; ++jj)
        Yc1[wv * 16 + lg * 4 + jj][ch * 16 + j] = acc[ch][jj];
  }
  if (wv < 4) {
    int kb = wv ^ 1;
    bf16x8 ka0 = pool_frag(Ks, kb * 64 + 4 * j, 4, lg, 0.25f);
    bf16x8 ka1 = pool_frag(Ks, kb * 64 + 4 * j, 4, 4 + lg, 0.25f);
    bf16x8 qb0 = pool_frag(Qs, wv * 64 + 4 * j, 4, lg, 0.25f);
    bf16x8 qb1 = pool_frag(Qs, wv * 64 + 4 * j, 4, 4 + lg, 0.25f);
    float as;
    bf16x8 pa = qk_softmax(ka0, ka1, qb0, qb1, lane, &as);
    if (lg == 0) SUMc[128 + wv * 16 + j] = as;
    int rb = kb * 64 + (lg & 1) * 32;
    f32x4 acc[4];
#pragma unroll
    for (int ch = 0; ch < 4; ++ch) {
      bf16x8 vb = vt_frag<2>(Vt, ch * 16 + j, rb);
      acc[ch] = __builtin_amdgcn_mfma_f32_16x16x32_bf16(pa, vb, f32x4{0.f,0.f,0.f,0.f}, 0, 0, 0);
    }
#pragma unroll
    for (int ch = 0; ch < 4; ++ch)
#pragma unroll
      for (int jj = 0; jj < 4; ++jj)
        Yc2[wv * 16 + lg * 4 + jj][ch * 16 + j] = acc[ch][jj];
  }
  if (wv >= 6) {
    int w3 = wv - 6;
    int kb = w3 ^ 1;
    bf16x8 ka0 = pool_frag(Ks, kb * 128 + 8 * j, 8, lg, 0.125f);
    bf16x8 ka1 = pool_frag(Ks, kb * 128 + 8 * j, 8, 4 + lg, 0.125f);
    bf16x8 qb0 = pool_frag(Qs, w3 * 128 + 8 * j, 8, lg, 0.125f);
    bf16x8 qb1 = pool_frag(Qs, w3 * 128 + 8 * j, 8, 4 + lg, 0.125f);
    float as;
    bf16x8 pa = qk_softmax(ka0, ka1, qb0, qb1, lane, &as);
    if (lg == 0) SUMc[192 + w3 * 16 + j] = as;
    int rb = kb * 128 + (lg & 1) * 64;
    f32x4 acc[4];
#pragma unroll
    for (int ch = 0; ch < 4; ++ch) {
      bf16x8 vb = vt_frag<3>(Vt, ch * 16 + j, rb);
      acc[ch] = __builtin_amdgcn_mfma_f32_16x16x32_bf16(pa, vb, f32x4{0.f,0.f,0.f,0.f}, 0, 0, 0);
    }
#pragma unroll
    for (int ch = 0; ch < 4; ++ch)
#pragma unroll
      for (int jj = 0; jj < 4; ++jj)
        Yc3[w3 * 16 + lg * 4 + jj][ch * 16 + j] = acc[ch][jj];
  }
  __syncthreads();

  const int batch = Bi >> 4, h = Bi & 15;
  const int offr[5] = {0, 512, 768, 896, 960};
#pragma unroll
  for (int bb = 0; bb < 2; ++bb) {
    int b = wv * 2 + bb;
    bf16x8 ka0 = rd_frag(Ks, b * 16 + j, lg);
    bf16x8 ka1 = rd_frag(Ks, b * 16 + j, 4 + lg);
    bf16x8 qb0 = rd_frag(Qs, b * 16 + j, lg);
    bf16x8 qb1 = rd_frag(Qs, b * 16 + j, 4 + lg);
    float as;
    bf16x8 pa = qk_softmax(ka0, ka1, qb0, qb1, lane, &as);
    float av[4];
#pragma unroll
    for (int jj = 0; jj < 4; ++jj)
      av[jj] = __int_as_float(__builtin_amdgcn_ds_bpermute((lg * 4 + jj) << 2,
                                                           __float_as_int(as)));
    int rb = b * 16 + (lg & 1) * 8;
    f32x4 acc[4];
#pragma unroll
    for (int ch = 0; ch < 4; ++ch) {
      bf16x8 vb = *(const bf16x8*)(Vt + (ch * 16 + j) * 266 + rb);
      acc[ch] = __builtin_amdgcn_mfma_f32_16x16x32_bf16(pa, vb, f32x4{0.f,0.f,0.f,0.f}, 0, 0, 0);
    }
    const int i4 = ci * 16 + b;
    float a4 = 0;
    float y4v[4] = {0, 0, 0, 0};
#pragma unroll
    for (int l = 0; l < 5; ++l) {
      int Rl = 512 >> l;
      size_t idx = (size_t)Bi * Rl + (i4 >> l);
      a4 += alvl[(size_t)64 * offr[l] + idx];
      const float* yp = ylvl + (size_t)4096 * offr[l] + idx * 64;
#pragma unroll
      for (int ch = 0; ch < 4; ++ch) y4v[ch] += yp[ch * 16 + j];
    }
#pragma unroll
    for (int jj = 0; jj < 4; ++jj) {
      int r0 = b * 16 + lg * 4 + jj;
      float at = av[jj] + SUMc[r0 >> 1] + SUMc[128 + (r0 >> 2)] + SUMc[192 + (r0 >> 3)] + a4;
      float inv = 1.0f / (at + 1e-8f);
      size_t n = (size_t)ci * 256 + r0;
      u16* orow = outA + ((size_t)batch * 8192 + n) * 1024 + h * 64 + j;
#pragma unroll
      for (int ch = 0; ch < 4; ++ch) {
        float yt = acc[ch][jj] + Yc1[r0 >> 1][ch * 16 + j] + Yc2[r0 >> 2][ch * 16 + j] +
                   Yc3[r0 >> 3][ch * 16 + j] + y4v[ch];
        orow[ch * 16] = f2bf(yt * inv);
      }
    }
  }
}

// ---------------- host ----------------
extern "C" void kernel_launch(void* const* d_in, const int* in_sizes, int n_in,
                              void* d_out, int out_size, void* d_ws, size_t ws_size,
                              hipStream_t stream) {
  const float* x = (const float*)d_in[0];
  const float* w_qkv = (const float*)d_in[1];
  const float* w_out = (const float*)d_in[2];
  const float* b_out = (const float*)d_in[3];
  float* out = (float*)d_out;

  char* ws = (char*)d_ws;
  size_t off = 0;
  auto alloc = [&](size_t bytes) -> char* {
    char* p = ws + off;
    off += (bytes + 255) & ~(size_t)255;
    return p;
  };
  u16* xb = (u16*)alloc(33554432ull * 2);
  u16* wqkvT = (u16*)alloc(3072ull * 1024 * 2);
  u16* woutT = (u16*)alloc(1024ull * 1024 * 2);
  u16* q0 = (u16*)alloc(67108864ull);
  u16* k0 = (u16*)alloc(67108864ull);
  u16* v0 = (u16*)alloc(67108864ull);
  u16* q4 = (u16*)alloc(4194304ull);
  u16* k4 = (u16*)alloc(4194304ull);
  u16* v4 = (u16*)alloc(4194304ull);
  u16* qc = (u16*)alloc(3932160ull);
  u16* kc = (u16*)alloc(3932160ull);
  u16* vc = (u16*)alloc(3932160ull);
  float* ylvl = (float*)alloc(16252928ull);
  float* alvl = (float*)alloc(253952ull);
  (void)ws_size; (void)in_sizes; (void)n_in; (void)out_size;

  cast_bf16<<<2048, 256, 0, stream>>>(x, xb, 33554432 / 4);
  transpose_cast<<<dim3(3072 / 32, 1024 / 32), 256, 0, stream>>>(w_qkv, wqkvT, 1024, 3072);
  transpose_cast<<<dim3(1024 / 32, 1024 / 32), 256, 0, stream>>>(w_out, woutT, 1024, 1024);

  gemm32<0><<<1536, 512, 0, stream>>>(xb, wqkvT, 32768, 3072, 1024, 12,
                                      q0, k0, v0, q4, k4, v4, nullptr, nullptr);

  pool_all4<<<dim3(3840, 3), 256, 0, stream>>>(q4, k4, v4, qc, kc, vc);
  hattn_coarse<<<dim3(62, 64), 256, 0, stream>>>(q4, k4, v4, qc, kc, vc, ylvl, alvl);
  attn_fine<<<dim3(32, 64), 512, 0, stream>>>(q0, k0, v0, ylvl, alvl, xb);

  gemm32<1><<<512, 512, 0, stream>>>(xb, woutT, 32768, 1024, 1024, 4,
                                     nullptr, nullptr, nullptr,
                                     nullptr, nullptr, nullptr, out, b_out);
}

// Round 12
// 469.218 us; speedup vs baseline: 1.4107x; 1.4107x over previous
//
#include <hip/hip_runtime.h>

typedef unsigned short u16;
typedef unsigned int u32;
typedef __bf16 bf16x8 __attribute__((ext_vector_type(8)));
typedef float f32x4 __attribute__((ext_vector_type(4)));

__device__ inline float bf2f(u16 u) { u32 x = ((u32)u) << 16; return __uint_as_float(x); }
__device__ inline u16 f2bf(float f) {
  u32 x = __float_as_uint(f);
  u32 r = (x + 0x7FFFu + ((x >> 16) & 1u)) >> 16;  // RNE
  return (u16)r;
}
__device__ inline u32 pack2(float lo, float hi) {
  return (u32)f2bf(lo) | ((u32)f2bf(hi) << 16);
}

// ---------------- cast x (f32 -> bf16) ----------------
__global__ __launch_bounds__(256) void cast_bf16(const float* __restrict__ s,
                                                 u16* __restrict__ d, int n4) {
  const float4* s4 = (const float4*)s;
  u32* d2 = (u32*)d;
  int i = blockIdx.x * 256 + threadIdx.x;
  int stride = gridDim.x * 256;
  for (; i < n4; i += stride) {
    float4 f = s4[i];
    d2[2 * i]     = pack2(f.x, f.y);
    d2[2 * i + 1] = pack2(f.z, f.w);
  }
}

// ---------------- transpose + cast: src[R][C] f32 -> dst[C][R] bf16 ----------------
__global__ __launch_bounds__(256) void transpose_cast(const float* __restrict__ src,
                                                      u16* __restrict__ dst, int R, int C) {
  __shared__ float tile[32][33];
  int bx = blockIdx.x, by = blockIdx.y;
  int tx = threadIdx.x & 31, ty = threadIdx.x >> 5;
  for (int rr = ty; rr < 32; rr += 8)
    tile[rr][tx] = src[(size_t)(by * 32 + rr) * C + bx * 32 + tx];
  __syncthreads();
  for (int rr = ty; rr < 32; rr += 8)
    dst[(size_t)(bx * 32 + rr) * R + by * 32 + tx] = f2bf(tile[tx][rr]);
}

// ---------------- 256x256 8-phase (2 K-tiles/iter) bf16 MFMA GEMM (r6 exact, best measured) ----------------
#define MFMAQ(AF, BF, MO, NO)                                                     \
  _Pragma("unroll") for (int mf = 0; mf < 4; ++mf)                                \
  _Pragma("unroll") for (int nf = 0; nf < 2; ++nf)                                \
  _Pragma("unroll") for (int kq = 0; kq < 2; ++kq)                                \
    acc[(MO) + mf][(NO) + nf] = __builtin_amdgcn_mfma_f32_16x16x32_bf16(          \
        AF[mf][kq], BF[nf][kq], acc[(MO) + mf][(NO) + nf], 0, 0, 0);

#define PH_OPEN12                                                                 \
  asm volatile("s_waitcnt lgkmcnt(8)" ::: "memory");                              \
  __builtin_amdgcn_s_barrier();                                                   \
  asm volatile("s_waitcnt lgkmcnt(0)" ::: "memory");                              \
  __builtin_amdgcn_sched_barrier(0);                                              \
  __builtin_amdgcn_s_setprio(1);

#define PH_OPEN                                                                   \
  __builtin_amdgcn_s_barrier();                                                   \
  asm volatile("s_waitcnt lgkmcnt(0)" ::: "memory");                              \
  __builtin_amdgcn_sched_barrier(0);                                              \
  __builtin_amdgcn_s_setprio(1);

#define PH_CLOSE                                                                  \
  __builtin_amdgcn_s_setprio(0);                                                  \
  __builtin_amdgcn_s_barrier();                                                   \
  __builtin_amdgcn_sched_barrier(0);

#define PH_CLOSE_VM                                                               \
  __builtin_amdgcn_s_setprio(0);                                                  \
  asm volatile("s_waitcnt vmcnt(4)" ::: "memory");                                \
  __builtin_amdgcn_s_barrier();                                                   \
  __builtin_amdgcn_sched_barrier(0);

template <int EPI>
__global__ __launch_bounds__(512, 2) void gemm8p(
    const u16* __restrict__ A, const u16* __restrict__ Bt, int M, int N, int K, int NB,
    u16* __restrict__ q0, u16* __restrict__ k0, u16* __restrict__ v0,
    u16* __restrict__ q4, u16* __restrict__ k4, u16* __restrict__ v4,
    float* __restrict__ out, const float* __restrict__ bias) {
  __shared__ u16 lds[2][2][16384];
  const int tid = threadIdx.x;
  const int lane = tid & 63;
  const int wave = tid >> 6;
  const int wm = wave >> 2, wn = wave & 3;
  const int lr = lane & 15, lg = lane >> 4;

  const int nwg = gridDim.x;
  const int bid = blockIdx.x;
  const int swz = (bid & 7) * (nwg >> 3) + (bid >> 3);
  const int m0 = (swz / NB) * 256;
  const int n0 = (swz % NB) * 256;
  const int NT = K >> 6;
  const int NI = NT >> 1;

  auto stage_half = [&](int buf, int ht, int kt_) {
    const u16* src = (ht < 2) ? A : Bt;
    const int r0 = (ht < 2) ? m0 : n0;
    u16* ldsop = &lds[buf][ht >> 1][0];
#pragma unroll
    for (int ii = 0; ii < 2; ++ii) {
      int c2 = ((ht & 1) * 2 + ii) * 512 + tid;
      int row = c2 >> 3, ps = c2 & 7;
      int ks = ps ^ (row & 7);
      const u16* g = src + (size_t)(r0 + row) * K + kt_ + ks * 8;
      char* l = (char*)ldsop + (size_t)((((ht & 1) * 2 + ii) * 512 + (tid & ~63)) * 16);
      __builtin_amdgcn_global_load_lds((const __attribute__((address_space(1))) void*)g,
                                       (__attribute__((address_space(3))) void*)l, 16, 0, 0);
    }
  };
  auto rdA = [&](int c, int mf, int kq) -> bf16x8 {
    int rl = wm * 128 + mf * 16 + lr;
    int sl = (kq * 4 + lg) ^ (rl & 7);
    return *(const bf16x8*)(&lds[c][0][rl * 64 + sl * 8]);
  };
  auto rdB = [&](int c, int nf, int kq) -> bf16x8 {
    int rl = wn * 64 + nf * 16 + lr;
    int sl = (kq * 4 + lg) ^ (rl & 7);
    return *(const bf16x8*)(&lds[c][1][rl * 64 + sl * 8]);
  };

  f32x4 acc[8][4];
#pragma unroll
  for (int mf = 0; mf < 8; ++mf)
#pragma unroll
    for (int nf = 0; nf < 4; ++nf) acc[mf][nf] = f32x4{0.f, 0.f, 0.f, 0.f};

  stage_half(0, 2, 0); stage_half(0, 3, 0); stage_half(0, 0, 0); stage_half(0, 1, 0);
  stage_half(1, 2, 64); stage_half(1, 3, 64);
  asm volatile("s_waitcnt vmcnt(4)" ::: "memory");
  __builtin_amdgcn_s_barrier();
  __builtin_amdgcn_sched_barrier(0);

  bf16x8 afA[4][2], afB[4][2], bA[2][2], bB[2][2];
  for (int it = 0; it < NI; ++it) {
    const int kO  = (2 * it + 1) << 6;
    const int t2  = 2 * it + 2, t3 = 2 * it + 3;
    const int kE2 = ((t2 < NT) ? t2 : NT - 1) << 6;
    const int kO2 = ((t3 < NT) ? t3 : NT - 1) << 6;

#pragma unroll
    for (int mf = 0; mf < 4; ++mf) { afA[mf][0] = rdA(0, mf, 0); afA[mf][1] = rdA(0, mf, 1); }
#pragma unroll
    for (int nf = 0; nf < 2; ++nf) { bA[nf][0] = rdB(0, nf, 0); bA[nf][1] = rdB(0, nf, 1); }
    stage_half(1, 0, kO);
    PH_OPEN12 MFMAQ(afA, bA, 0, 0) PH_CLOSE
#pragma unroll
    for (int nf = 0; nf < 2; ++nf) { bB[nf][0] = rdB(0, 2 + nf, 0); bB[nf][1] = rdB(0, 2 + nf, 1); }
    stage_half(1, 1, kO);
    PH_OPEN MFMAQ(afA, bB, 0, 2) PH_CLOSE
#pragma unroll
    for (int mf = 0; mf < 4; ++mf) { afB[mf][0] = rdA(0, 4 + mf, 0); afB[mf][1] = rdA(0, 4 + mf, 1); }
    stage_half(0, 2, kE2);
    PH_OPEN MFMAQ(afB, bB, 4, 2) PH_CLOSE
    stage_half(0, 3, kE2);
    PH_OPEN MFMAQ(afB, bA, 4, 0) PH_CLOSE_VM
#pragma unroll
    for (int mf = 0; mf < 4; ++mf) { afA[mf][0] = rdA(1, mf, 0); afA[mf][1] = rdA(1, mf, 1); }
#pragma unroll
    for (int nf = 0; nf < 2; ++nf) { bA[nf][0] = rdB(1, nf, 0); bA[nf][1] = rdB(1, nf, 1); }
    stage_half(0, 0, kE2);
    PH_OPEN12 MFMAQ(afA, bA, 0, 0) PH_CLOSE
#pragma unroll
    for (int nf = 0; nf < 2; ++nf) { bB[nf][0] = rdB(1, 2 + nf, 0); bB[nf][1] = rdB(1, 2 + nf, 1); }
    stage_half(0, 1, kE2);
    PH_OPEN MFMAQ(afA, bB, 0, 2) PH_CLOSE
#pragma unroll
    for (int mf = 0; mf < 4; ++mf) { afB[mf][0] = rdA(1, 4 + mf, 0); afB[mf][1] = rdA(1, 4 + mf, 1); }
    stage_half(1, 2, kO2);
    PH_OPEN MFMAQ(afB, bB, 4, 2) PH_CLOSE
    stage_half(1, 3, kO2);
    PH_OPEN MFMAQ(afB, bA, 4, 0) PH_CLOSE_VM
  }
  asm volatile("s_waitcnt vmcnt(0)" ::: "memory");

#pragma unroll
  for (int mf = 0; mf < 8; ++mf) {
#pragma unroll
    for (int nf = 0; nf < 4; ++nf) {
      int col = n0 + wn * 64 + nf * 16 + lr;
      if (EPI == 0) {
        int p = col >> 10, cc = col & 1023;
        int h = cc >> 6, d = cc & 63;
        u16* dst = (p == 0) ? q0 : (p == 1) ? k0 : v0;
        float sc = (p == 0) ? 0.125f : 1.0f;
#pragma unroll
        for (int jj = 0; jj < 4; ++jj) {
          int row = m0 + wm * 128 + mf * 16 + lg * 4 + jj;
          int b = row >> 13, nn = row & 8191;
          dst[((size_t)((b << 4) + h) * 8192 + nn) * 64 + d] = f2bf(acc[mf][nf][jj] * sc);
        }
        float s4 = acc[mf][nf][0] + acc[mf][nf][1] + acc[mf][nf][2] + acc[mf][nf][3];
        s4 += __shfl_xor(s4, 16);
        s4 += __shfl_xor(s4, 32);
        if (lane < 16) {
          int row = m0 + wm * 128 + mf * 16;
          int b = row >> 13, n4 = (row & 8191) >> 4;
          u16* dst4 = (p == 0) ? q4 : (p == 1) ? k4 : v4;
          float val = (p == 2) ? s4 : s4 * 0.0625f;
          if (p == 0) val *= 0.125f;
          dst4[((size_t)((b << 4) + h) * 512 + n4) * 64 + d] = f2bf(val);
        }
      } else {
        float bv = bias[col];
#pragma unroll
        for (int jj = 0; jj < 4; ++jj) {
          int row = m0 + wm * 128 + mf * 16 + lg * 4 + jj;
          out[(size_t)row * N + col] = acc[mf][nf][jj] + bv;
        }
      }
    }
  }
}

// ---------------- fused pooling: levels 5-8 directly from level 4 ----------------
__global__ __launch_bounds__(256) void pool_all4(
    const u16* __restrict__ q4, const u16* __restrict__ k4, const u16* __restrict__ v4,
    u16* __restrict__ qd, u16* __restrict__ kd, u16* __restrict__ vd) {
  int t = blockIdx.x * 256 + threadIdx.x;
  if (t >= 983040) return;  // 64 * 480 * 32
  int arr = blockIdx.y;
  int col = t & 31;
  int rr = t >> 5;
  int Bi = rr / 480;
  int r = rr % 480;
  int base, w, Nl;
  if (r < 256)      { base = 0;   w = 2;  Nl = 256; }
  else if (r < 384) { base = 256; w = 4;  Nl = 128; r -= 256; }
  else if (r < 448) { base = 384; w = 8;  Nl = 64;  r -= 384; }
  else              { base = 448; w = 16; Nl = 32;  r -= 448; }
  const u32* s = (const u32*)(arr == 0 ? q4 : arr == 1 ? k4 : v4);
  const u32* src = s + ((size_t)Bi * 512 + (size_t)r * w) * 32 + col;
  float lo = 0, hi = 0;
  for (int m = 0; m < w; ++m) {
    u32 u = src[(size_t)m * 32];
    lo += bf2f((u16)u); hi += bf2f((u16)(u >> 16));
  }
  float sc = (arr == 2) ? 1.0f : (1.0f / (float)w);
  u32* d = (u32*)(arr == 0 ? qd : arr == 1 ? kd : vd);
  d[(size_t)2048 * base + ((size_t)Bi * Nl + r) * 32 + col] = pack2(lo * sc, hi * sc);
}

// ---------------- coarse attention: all levels 4-8 in one launch, always flip ----------------
__global__ __launch_bounds__(256) void hattn_coarse(
    const u16* __restrict__ q4, const u16* __restrict__ k4, const u16* __restrict__ v4,
    const u16* __restrict__ qc, const u16* __restrict__ kc, const u16* __restrict__ vc,
    float* __restrict__ ylvl, float* __restrict__ alvl) {
  __shared__ float qs[16][68], ks[16][68], vs[16][68];
  __shared__ float As[16][17];
  const int bx = blockIdx.x, Bi = blockIdx.y;
  int lvl, jb;
  if (bx < 32)      { lvl = 0; jb = bx; }
  else if (bx < 48) { lvl = 1; jb = bx - 32; }
  else if (bx < 56) { lvl = 2; jb = bx - 48; }
  else if (bx < 60) { lvl = 3; jb = bx - 56; }
  else              { lvl = 4; jb = bx - 60; }
  const int N = 512 >> lvl;
  const int srcb[5] = {0, 0, 256, 384, 448};
  const int offr[5] = {0, 512, 768, 896, 960};
  const u16* qp = (lvl == 0) ? q4 : qc + (size_t)4096 * srcb[lvl];
  const u16* kp = (lvl == 0) ? k4 : kc + (size_t)4096 * srcb[lvl];
  const u16* vp = (lvl == 0) ? v4 : vc + (size_t)4096 * srcb[lvl];
  const int tid = threadIdx.x;
  const int jk = jb ^ 1;
  const u32* qg = (const u32*)(qp + ((size_t)Bi * N + jb * 16) * 64);
  const u32* kg = (const u32*)(kp + ((size_t)Bi * N + jk * 16) * 64);
  const u32* vg = (const u32*)(vp + ((size_t)Bi * N + jk * 16) * 64);
#pragma unroll
  for (int u = tid; u < 512; u += 256) {
    int row = u >> 5, dp = (u & 31) * 2;
    u32 a = qg[u]; qs[row][dp] = bf2f((u16)a); qs[row][dp + 1] = bf2f((u16)(a >> 16));
    u32 b = kg[u]; ks[row][dp] = bf2f((u16)b); ks[row][dp + 1] = bf2f((u16)(b >> 16));
    u32 c = vg[u]; vs[row][dp] = bf2f((u16)c); vs[row][dp + 1] = bf2f((u16)(c >> 16));
  }
  __syncthreads();
  const int i = tid >> 4, j = tid & 15;
  float s = 0.f;
  const float4* qv = (const float4*)&qs[i][0];
  const float4* kv = (const float4*)&ks[j][0];
#pragma unroll
  for (int d4 = 0; d4 < 16; ++d4) {
    float4 a = qv[d4], b = kv[d4];
    s += a.x * b.x + a.y * b.y + a.z * b.z + a.w * b.w;
  }
  float mx = s;
#pragma unroll
  for (int off = 8; off; off >>= 1) mx = fmaxf(mx, __shfl_xor(mx, off, 16));
  float aexp = __expf(s - mx);
  float asum = aexp;
#pragma unroll
  for (int off = 8; off; off >>= 1) asum += __shfl_xor(asum, off, 16);
  As[i][j] = aexp;
  __syncthreads();
  float y0 = 0, y1 = 0, y2 = 0, y3 = 0;
  const int d0 = j * 4;
#pragma unroll
  for (int jj = 0; jj < 16; ++jj) {
    float av = As[i][jj];
    const float4 vv = *(const float4*)&vs[jj][d0];
    y0 += av * vv.x; y1 += av * vv.y; y2 += av * vv.z; y3 += av * vv.w;
  }
  const int nf = jb * 16 + i;
  float* yo = ylvl + (size_t)4096 * offr[lvl] + ((size_t)Bi * N + nf) * 64 + d0;
  yo[0] = y0; yo[1] = y1; yo[2] = y2; yo[3] = y3;
  if (j == 0) alvl[(size_t)64 * offr[lvl] + (size_t)Bi * N + nf] = asum;
}

// ================= fused fine attention (levels 3..0), MFMA =================
union F8 { u32 w[4]; bf16x8 v; };

__device__ inline void acc_row8(const u16* p, float* a) {
  const u32* qw = (const u32*)p;
#pragma unroll
  for (int m = 0; m < 4; ++m) {
    u32 u = qw[m];
    a[2 * m]     += bf2f((u16)u);
    a[2 * m + 1] += bf2f((u16)(u >> 16));
  }
}
__device__ inline bf16x8 mk8(const float* a, float s) {
  F8 f;
#pragma unroll
  for (int m = 0; m < 4; ++m) f.w[m] = pack2(a[2 * m] * s, a[2 * m + 1] * s);
  return f.v;
}
__device__ inline bf16x8 pool_frag(const u16* arr, int row0, int cnt, int slotq, float scale) {
  float a[8] = {0, 0, 0, 0, 0, 0, 0, 0};
  for (int m = 0; m < cnt; ++m) {
    int r = row0 + m;
    acc_row8(arr + r * 64 + ((slotq ^ (r & 7)) * 8), a);
  }
  return mk8(a, scale);
}
__device__ inline bf16x8 rd_frag(const u16* arr, int r, int slotq) {
  return *(const bf16x8*)(arr + r * 64 + ((slotq ^ (r & 7)) * 8));
}
template <int LVL>
__device__ inline bf16x8 vt_frag(const u16* Vt, int c, int rbase) {
  float a[8] = {0, 0, 0, 0, 0, 0, 0, 0};
  const u32* p = (const u32*)(Vt + c * 266 + rbase);
#pragma unroll
  for (int g = 0; g < (1 << LVL); ++g) {
#pragma unroll
    for (int m = 0; m < 4; ++m) {
      u32 u = p[g * 4 + m];
      int t = g * 8 + 2 * m;
      a[t >> LVL]       += bf2f((u16)u);
      a[(t + 1) >> LVL] += bf2f((u16)(u >> 16));
    }
  }
  return mk8(a, 1.0f);
}

__device__ inline bf16x8 qk_softmax(bf16x8 ka0, bf16x8 ka1, bf16x8 qb0, bf16x8 qb1,
                                    int lane, float* asum_out) {
  f32x4 s = {0.f, 0.f, 0.f, 0.f};
  s = __builtin_amdgcn_mfma_f32_16x16x32_bf16(ka0, qb0, s, 0, 0, 0);
  s = __builtin_amdgcn_mfma_f32_16x16x32_bf16(ka1, qb1, s, 0, 0, 0);
  float mx = fmaxf(fmaxf(s[0], s[1]), fmaxf(s[2], s[3]));
  mx = fmaxf(mx, __shfl_xor(mx, 32));
  mx = fmaxf(mx, __shfl_xor(mx, 16));
  float p0 = __expf(s[0] - mx), p1 = __expf(s[1] - mx);
  float p2 = __expf(s[2] - mx), p3 = __expf(s[3] - mx);
  float as = p0 + p1 + p2 + p3;
  as += __shfl_xor(as, 32);
  as += __shfl_xor(as, 16);
  *asum_out = as;
  u32 pk01 = pack2(p0, p1), pk23 = pack2(p2, p3);
  int jq = lane & 15, lg = lane >> 4;
  int a1 = ((((lg * 2) * 16) + jq) & 63) << 2;
  int a2 = ((((lg * 2 + 1) * 16) + jq) & 63) << 2;
  F8 f;
  f.w[0] = (u32)__builtin_amdgcn_ds_bpermute(a1, (int)pk01);
  f.w[1] = (u32)__builtin_amdgcn_ds_bpermute(a1, (int)pk23);
  f.w[2] = (u32)__builtin_amdgcn_ds_bpermute(a2, (int)pk01);
  f.w[3] = (u32)__builtin_amdgcn_ds_bpermute(a2, (int)pk23);
  if (lg >= 2) { f.w[0] = 0; f.w[1] = 0; f.w[2] = 0; f.w[3] = 0; }
  return f.v;
}

__global__ __launch_bounds__(512, 1) void attn_fine(
    const u16* __restrict__ q, const u16* __restrict__ k, const u16* __restrict__ v,
    const float* __restrict__ ylvl, const float* __restrict__ alvl,
    u16* __restrict__ outA) {
  __shared__ u16 Qs[16384];
  __shared__ u16 Ks[16384];
  __shared__ u16 Vt[17024];       // [64][266] transposed, odd-word row stride
  __shared__ float Yc1[128][68];
  __shared__ float Yc2[64][68];
  __shared__ float Yc3[32][68];
  __shared__ float SUMc[224];
  const int tid = threadIdx.x;
  const int lane = tid & 63;
  const int wv = tid >> 6;
  const int j = lane & 15, lg = lane >> 4;
  const int ci = blockIdx.x, Bi = blockIdx.y;
  const size_t gbase = ((size_t)Bi * 8192 + (size_t)ci * 256) * 64;

#pragma unroll
  for (int it = 0; it < 4; ++it) {
    int sidx = it * 512 + tid;
    int row = sidx >> 3, ps = sidx & 7;
    int ks_ = ps ^ (row & 7);
    const u16* gq = q + gbase + (size_t)row * 64 + ks_ * 8;
    const u16* gk = k + gbase + (size_t)row * 64 + ks_ * 8;
    char* lq = (char*)Qs + (size_t)(it * 512 + (tid & ~63)) * 16;
    char* lk = (char*)Ks + (size_t)(it * 512 + (tid & ~63)) * 16;
    __builtin_amdgcn_global_load_lds((const __attribute__((address_space(1))) void*)gq,
                                     (__attribute__((address_space(3))) void*)lq, 16, 0, 0);
    __builtin_amdgcn_global_load_lds((const __attribute__((address_space(1))) void*)gk,
                                     (__attribute__((address_space(3))) void*)lk, 16, 0, 0);
  }
  {
    const uint4* gv = (const uint4*)(v + gbase);
    u32* Vt32 = (u32*)Vt;
#pragma unroll
    for (int it = 0; it < 2; ++it) {
      int i = it * 512 + tid;
      int r2 = i >> 3, cg = i & 7, c0 = cg * 8;
      uint4 a = gv[(size_t)(2 * r2) * 8 + cg];
      uint4 b = gv[(size_t)(2 * r2 + 1) * 8 + cg];
      const u16* pa = (const u16*)&a;
      const u16* pb = (const u16*)&b;
#pragma unroll
      for (int m = 0; m < 8; ++m)
        Vt32[(c0 + m) * 133 + r2] = (u32)pa[m] | ((u32)pb[m] << 16);
    }
  }
  __syncthreads();

  {
    int kb = wv ^ 1;
    bf16x8 ka0 = pool_frag(Ks, kb * 32 + 2 * j, 2, lg, 0.5f);
    bf16x8 ka1 = pool_frag(Ks, kb * 32 + 2 * j, 2, 4 + lg, 0.5f);
    bf16x8 qb0 = pool_frag(Qs, wv * 32 + 2 * j, 2, lg, 0.5f);
    bf16x8 qb1 = pool_frag(Qs, wv * 32 + 2 * j, 2, 4 + lg, 0.5f);
    float as;
    bf16x8 pa = qk_softmax(ka0, ka1, qb0, qb1, lane, &as);
    if (lg == 0) SUMc[wv * 16 + j] = as;
    int rb = kb * 32 + (lg & 1) * 16;
    f32x4 acc[4];
#pragma unroll
    for (int ch = 0; ch < 4; ++ch) {
      bf16x8 vb = vt_frag<1>(Vt, ch * 16 + j, rb);
      acc[ch] = __builtin_amdgcn_mfma_f32_16x16x32_bf16(pa, vb, f32x4{0.f,0.f,0.f,0.f}, 0, 0, 0);
    }
#pragma unroll
    for (int ch = 0; ch < 4; ++ch)
#pragma unroll
      for (int jj = 0; jj < 4; ++jj)
        Yc1[wv * 16 + lg * 4 + jj][ch * 16 + j] = acc[ch][jj];
  }
  if (wv < 4) {
    int kb = wv ^ 1;
    bf16x8 ka0 = pool_frag(Ks, kb * 64 + 4 * j, 4, lg, 0.25f);
    bf16x8 ka1 = pool_frag(Ks, kb * 64 + 4 * j, 4, 4 + lg, 0.25f);
    bf16x8 qb0 = pool_frag(Qs, wv * 64 + 4 * j, 4, lg, 0.25f);
    bf16x8 qb1 = pool_frag(Qs, wv * 64 + 4 * j, 4, 4 + lg, 0.25f);
    float as;
    bf16x8 pa = qk_softmax(ka0, ka1, qb0, qb1, lane, &as);
    if (lg == 0) SUMc[128 + wv * 16 + j] = as;
    int rb = kb * 64 + (lg & 1) * 32;
    f32x4 acc[4];
#pragma unroll
    for (int ch = 0; ch < 4; ++ch) {
      bf16x8 vb = vt_frag<2>(Vt, ch * 16 + j, rb);
      acc[ch] = __builtin_amdgcn_mfma_f32_16x16x32_bf16(pa, vb, f32x4{0.f,0.f,0.f,0.f}, 0, 0, 0);
    }
#pragma unroll
    for (int ch = 0; ch < 4; ++ch)
#pragma unroll
      for (int jj = 0; jj < 4; ++jj)
        Yc2[wv * 16 + lg * 4 + jj][ch * 16 + j] = acc[ch][jj];
  }
  if (wv >= 6) {
    int w3 = wv - 6;
    int kb = w3 ^ 1;
    bf16x8 ka0 = pool_frag(Ks, kb * 128 + 8 * j, 8, lg, 0.125f);
    bf16x8 ka1 = pool_frag(Ks, kb * 128 + 8 * j, 8, 4 + lg, 0.125f);
    bf16x8 qb0 = pool_frag(Qs, w3 * 128 + 8 * j, 8, lg, 0.125f);
    bf16x8 qb1 = pool_frag(Qs, w3 * 128 + 8 * j, 8, 4 + lg, 0.125f);
    float as;
    bf16x8 pa = qk_softmax(ka0, ka1, qb0, qb1, lane, &as);
    if (lg == 0) SUMc[192 + w3 * 16 + j] = as;
    int rb = kb * 128 + (lg & 1) * 64;
    f32x4 acc[4];
#pragma unroll
    for (int ch = 0; ch < 4; ++ch) {
      bf16x8 vb = vt_frag<3>(Vt, ch * 16 + j, rb);
      acc[ch] = __builtin_amdgcn_mfma_f32_16x16x32_bf16(pa, vb, f32x4{0.f,0.f,0.f,0.f}, 0, 0, 0);
    }
#pragma unroll
    for (int ch = 0; ch < 4; ++ch)
#pragma unroll
      for (int jj = 0; jj < 4; ++jj)
        Yc3[w3 * 16 + lg * 4 + jj][ch * 16 + j] = acc[ch][jj];
  }
  __syncthreads();

  const int batch = Bi >> 4, h = Bi & 15;
  const int offr[5] = {0, 512, 768, 896, 960};
#pragma unroll
  for (int bb = 0; bb < 2; ++bb) {
    int b = wv * 2 + bb;
    bf16x8 ka0 = rd_frag(Ks, b * 16 + j, lg);
    bf16x8 ka1 = rd_frag(Ks, b * 16 + j, 4 + lg);
    bf16x8 qb0 = rd_frag(Qs, b * 16 + j, lg);
    bf16x8 qb1 = rd_frag(Qs, b * 16 + j, 4 + lg);
    float as;
    bf16x8 pa = qk_softmax(ka0, ka1, qb0, qb1, lane, &as);
    float av[4];
#pragma unroll
    for (int jj = 0; jj < 4; ++jj)
      av[jj] = __int_as_float(__builtin_amdgcn_ds_bpermute((lg * 4 + jj) << 2,
                                                           __float_as_int(as)));
    int rb = b * 16 + (lg & 1) * 8;
    f32x4 acc[4];
#pragma unroll
    for (int ch = 0; ch < 4; ++ch) {
      bf16x8 vb = *(const bf16x8*)(Vt + (ch * 16 + j) * 266 + rb);
      acc[ch] = __builtin_amdgcn_mfma_f32_16x16x32_bf16(pa, vb, f32x4{0.f,0.f,0.f,0.f}, 0, 0, 0);
    }
    const int i4 = ci * 16 + b;
    float a4 = 0;
    float y4v[4] = {0, 0, 0, 0};
#pragma unroll
    for (int l = 0; l < 5; ++l) {
      int Rl = 512 >> l;
      size_t idx = (size_t)Bi * Rl + (i4 >> l);
      a4 += alvl[(size_t)64 * offr[l] + idx];
      const float* yp = ylvl + (size_t)4096 * offr[l] + idx * 64;
#pragma unroll
      for (int ch = 0; ch < 4; ++ch) y4v[ch] += yp[ch * 16 + j];
    }
#pragma unroll
    for (int jj = 0; jj < 4; ++jj) {
      int r0 = b * 16 + lg * 4 + jj;
      float at = av[jj] + SUMc[r0 >> 1] + SUMc[128 + (r0 >> 2)] + SUMc[192 + (r0 >> 3)] + a4;
      float inv = 1.0f / (at + 1e-8f);
      size_t n = (size_t)ci * 256 + r0;
      u16* orow = outA + ((size_t)batch * 8192 + n) * 1024 + h * 64 + j;
#pragma unroll
      for (int ch = 0; ch < 4; ++ch) {
        float yt = acc[ch][jj] + Yc1[r0 >> 1][ch * 16 + j] + Yc2[r0 >> 2][ch * 16 + j] +
                   Yc3[r0 >> 3][ch * 16 + j] + y4v[ch];
        orow[ch * 16] = f2bf(yt * inv);
      }
    }
  }
}

// ---------------- host ----------------
extern "C" void kernel_launch(void* const* d_in, const int* in_sizes, int n_in,
                              void* d_out, int out_size, void* d_ws, size_t ws_size,
                              hipStream_t stream) {
  const float* x = (const float*)d_in[0];
  const float* w_qkv = (const float*)d_in[1];
  const float* w_out = (const float*)d_in[2];
  const float* b_out = (const float*)d_in[3];
  float* out = (float*)d_out;

  char* ws = (char*)d_ws;
  size_t off = 0;
  auto alloc = [&](size_t bytes) -> char* {
    char* p = ws + off;
    off += (bytes + 255) & ~(size_t)255;
    return p;
  };
  u16* xb = (u16*)alloc(33554432ull * 2);
  u16* wqkvT = (u16*)alloc(3072ull * 1024 * 2);
  u16* woutT = (u16*)alloc(1024ull * 1024 * 2);
  u16* q0 = (u16*)alloc(67108864ull);
  u16* k0 = (u16*)alloc(67108864ull);
  u16* v0 = (u16*)alloc(67108864ull);
  u16* q4 = (u16*)alloc(4194304ull);
  u16* k4 = (u16*)alloc(4194304ull);
  u16* v4 = (u16*)alloc(4194304ull);
  u16* qc = (u16*)alloc(3932160ull);
  u16* kc = (u16*)alloc(3932160ull);
  u16* vc = (u16*)alloc(3932160ull);
  float* ylvl = (float*)alloc(16252928ull);
  float* alvl = (float*)alloc(253952ull);
  (void)ws_size; (void)in_sizes; (void)n_in; (void)out_size;

  cast_bf16<<<2048, 256, 0, stream>>>(x, xb, 33554432 / 4);
  transpose_cast<<<dim3(3072 / 32, 1024 / 32), 256, 0, stream>>>(w_qkv, wqkvT, 1024, 3072);
  transpose_cast<<<dim3(1024 / 32, 1024 / 32), 256, 0, stream>>>(w_out, woutT, 1024, 1024);

  gemm8p<0><<<1536, 512, 0, stream>>>(xb, wqkvT, 32768, 3072, 1024, 12,
                                      q0, k0, v0, q4, k4, v4, nullptr, nullptr);

  pool_all4<<<dim3(3840, 3), 256, 0, stream>>>(q4, k4, v4, qc, kc, vc);
  hattn_coarse<<<dim3(62, 64), 256, 0, stream>>>(q4, k4, v4, qc, kc, vc, ylvl, alvl);
  attn_fine<<<dim3(32, 64), 512, 0, stream>>>(q0, k0, v0, ylvl, alvl, xb);

  gemm8p<1><<<512, 512, 0, stream>>>(xb, woutT, 32768, 1024, 1024, 4,
                                     nullptr, nullptr, nullptr,
                                     nullptr, nullptr, nullptr, out, b_out);
}